// Round 6
// baseline (3942.068 us; speedup 1.0000x reference)
//
#include <hip/hip_runtime.h>

#define L2E 1.4426950408889634f
#define NEG_BIG (-1e30f)

static __device__ __forceinline__ float bf2f(unsigned short u) {
    unsigned int v = ((unsigned int)u) << 16;
    return __builtin_bit_cast(float, v);
}
static __device__ __forceinline__ unsigned short f2bf(float f) {
    unsigned int u = __builtin_bit_cast(unsigned int, f);
    u += 0x7fffu + ((u >> 16) & 1u);   // RNE
    return (unsigned short)(u >> 16);
}

// ---------------- 1) QKV (brute): acc = sum_c x[c][n]*w[o][c] ----------------
__global__ __launch_bounds__(256) void k_qkv_brute(const float* __restrict__ x,
                                                   const float* __restrict__ w,
                                                   unsigned short* __restrict__ qm,
                                                   unsigned short* __restrict__ km,
                                                   unsigned short* __restrict__ vm) {
    const int idx = blockIdx.x * 256 + threadIdx.x;   // n fastest: coalesced x, uniform w
    const int n = idx & 4095;
    const int o = idx >> 12;
    float acc = 0.f;
    for (int c = 0; c < 256; ++c)
        acc = fmaf(x[c * 4096 + n], w[o * 256 + c], acc);
    const unsigned short val = f2bf(acc);
    const int s = o >> 8, rem = o & 255, head = rem >> 5, t = rem & 31;
    unsigned short* dst = (s == 0) ? qm : (s == 1) ? km : vm;
    dst[((size_t)head * 4096 + n) * 32 + t] = val;
}

// ---------------- 2) attention (brute): one thread per (head, query) ----------------
__global__ __launch_bounds__(256) void k_attn_brute(const unsigned short* __restrict__ qm,
                                                    const unsigned short* __restrict__ km,
                                                    const unsigned short* __restrict__ vm,
                                                    unsigned short* __restrict__ ao) {
    const int idx = blockIdx.x * 256 + threadIdx.x;
    const int i = idx & 4095;     // query token
    const int h = idx >> 12;      // head
    const int di = i >> 8, hi = (i >> 4) & 15, wi = i & 15;

    float q[32];
    {
        const size_t qb = ((size_t)h * 4096 + i) * 32;
        #pragma unroll
        for (int t = 0; t < 32; ++t) q[t] = bf2f(qm[qb + t]);
    }

    const float scale2 = 0.17677669529663687f * L2E;   // (1/sqrt(32)) * log2(e)
    float m = NEG_BIG, l = 0.f, o[32];
    #pragma unroll
    for (int t = 0; t < 32; ++t) o[t] = 0.f;

    for (int j = 0; j < 4096; ++j) {
        const int dj = di - (j >> 8);
        const int hj = hi - ((j >> 4) & 15);
        const int wj = wi - (j & 15);
        if (dj * dj + hj * hj + wj * wj >= 100) continue;   // dist < 10

        const size_t kb = ((size_t)h * 4096 + j) * 32;      // wave-uniform -> broadcast
        float s = 0.f;
        #pragma unroll
        for (int t = 0; t < 32; ++t) s = fmaf(bf2f(km[kb + t]), q[t], s);
        s *= scale2;

        if (s > m) {
            const float alpha = exp2f(m - s);
            m = s;
            l *= alpha;
            #pragma unroll
            for (int t = 0; t < 32; ++t) o[t] *= alpha;
        }
        const float p = exp2f(s - m);
        l += p;
        const size_t vb = ((size_t)h * 4096 + j) * 32;
        #pragma unroll
        for (int t = 0; t < 32; ++t) o[t] = fmaf(bf2f(vm[vb + t]), p, o[t]);
    }

    const float inv = 1.f / l;   // j==i always unmasked -> l >= 1
    #pragma unroll
    for (int t = 0; t < 32; ++t)
        ao[(size_t)(h * 32 + t) * 4096 + i] = f2bf(o[t] * inv);
}

// ---------------- 3) proj (brute): out[o][n] = sum_c ao[c][n]*pw[o][c] + pb[o] ----------------
// OUTPUT IS FLOAT32 — the reference returns fp32, so d_out is float* per the harness contract.
__global__ __launch_bounds__(256) void k_proj_brute(const unsigned short* __restrict__ ao,
                                                    const float* __restrict__ pw,
                                                    const float* __restrict__ pb,
                                                    float* __restrict__ out) {
    const int idx = blockIdx.x * 256 + threadIdx.x;
    const int n = idx & 4095;
    const int o = idx >> 12;
    float acc = 0.f;
    for (int c = 0; c < 256; ++c)
        acc = fmaf(bf2f(ao[c * 4096 + n]), pw[o * 256 + c], acc);
    out[(size_t)o * 4096 + n] = acc + pb[o];
}

extern "C" void kernel_launch(void* const* d_in, const int* in_sizes, int n_in,
                              void* d_out, int out_size, void* d_ws, size_t ws_size,
                              hipStream_t stream) {
    const float* x      = (const float*)d_in[0];   // [1,256,16,16,16] fp32
    const float* qkv_w  = (const float*)d_in[1];   // [768,256] fp32
    const float* proj_w = (const float*)d_in[2];   // [256,256] fp32
    const float* proj_b = (const float*)d_in[3];   // [256] fp32
    float* out = (float*)d_out;                    // [256,4096] FLOAT32

    unsigned short* ws = (unsigned short*)d_ws;
    const size_t M = 1u << 20;          // 4096*256 elements
    unsigned short* qm = ws;            // [8][4096][32] bf16
    unsigned short* km = ws + 1 * M;    // [8][4096][32] bf16
    unsigned short* vm = ws + 2 * M;    // [8][4096][32] bf16
    unsigned short* ao = ws + 3 * M;    // [256][4096]  bf16   (total 8 MB)

    k_qkv_brute<<<dim3(12288), 256, 0, stream>>>(x, qkv_w, qm, km, vm);
    k_attn_brute<<<dim3(128), 256, 0, stream>>>(qm, km, vm, ao);
    k_proj_brute<<<dim3(4096), 256, 0, stream>>>(ao, proj_w, proj_b, out);
}

// Round 7
// 206.553 us; speedup vs baseline: 19.0850x; 19.0850x over previous
//
#include <hip/hip_runtime.h>

typedef __attribute__((ext_vector_type(8))) short short8;
typedef __attribute__((ext_vector_type(8))) unsigned short ushort8;
typedef __attribute__((ext_vector_type(4))) unsigned short ushort4v;
typedef __attribute__((ext_vector_type(4))) float floatx4;

#define L2E 1.4426950408889634f
#define NEG_BIG (-1e30f)

static __device__ __forceinline__ unsigned short f2bf(float f) {
    unsigned int u = __builtin_bit_cast(unsigned int, f);
    u += 0x7fffu + ((u >> 16) & 1u);   // RNE
    return (unsigned short)(u >> 16);
}

// ---------------- 0) fp32 -> bf16 weight conversion ----------------
__global__ __launch_bounds__(256) void k_cvt(const float* __restrict__ src,
                                             unsigned short* __restrict__ dst, int n4) {
    const int i = blockIdx.x * 256 + threadIdx.x;
    if (i < n4) {
        const float4 v = reinterpret_cast<const float4*>(src)[i];
        ushort4v o;
        o[0] = f2bf(v.x); o[1] = f2bf(v.y); o[2] = f2bf(v.z); o[3] = f2bf(v.w);
        reinterpret_cast<ushort4v*>(dst)[i] = o;
    }
}

// ---------------- 1) transpose+cast: x[256][4096] fp32 -> tokT[4096][256] bf16 ----------------
__global__ __launch_bounds__(256) void k_transpose(const float* __restrict__ x,
                                                   unsigned short* __restrict__ tokT) {
    __shared__ unsigned short tile[64][72];
    const int n0 = blockIdx.x * 64, c0 = blockIdx.y * 64;
    const int tid = threadIdx.x;
    {
        const int c_l = tid >> 2, nl0 = (tid & 3) * 16;
        const float4* src = reinterpret_cast<const float4*>(x + (size_t)(c0 + c_l) * 4096 + n0 + nl0);
        #pragma unroll
        for (int v = 0; v < 4; ++v) {
            const float4 f = src[v];
            tile[c_l][nl0 + v * 4 + 0] = f2bf(f.x);
            tile[c_l][nl0 + v * 4 + 1] = f2bf(f.y);
            tile[c_l][nl0 + v * 4 + 2] = f2bf(f.z);
            tile[c_l][nl0 + v * 4 + 3] = f2bf(f.w);
        }
    }
    __syncthreads();
    {
        const int n_l = tid >> 2, cl0 = (tid & 3) * 16;
        ushort8 a, b;
        #pragma unroll
        for (int i = 0; i < 8; ++i) {
            a[i] = tile[cl0 + i][n_l];
            b[i] = tile[cl0 + 8 + i][n_l];
        }
        ushort8* dst = reinterpret_cast<ushort8*>(tokT + (size_t)(n0 + n_l) * 256 + c0 + cl0);
        dst[0] = a;
        dst[1] = b;
    }
}

// ---------------- 2) QKV GEMM: qkv[n][o] = sum_c tokT[n][c] * w[o][c] ----------------
__global__ __launch_bounds__(256) void k_qkv(const unsigned short* __restrict__ tokT,
                                             const unsigned short* __restrict__ w,
                                             unsigned short* __restrict__ qm,
                                             unsigned short* __restrict__ km,
                                             unsigned short* __restrict__ vt) {
    const int tid = threadIdx.x;
    const int wave = tid >> 6, lane = tid & 63;
    const int l16 = lane & 15, quad = lane >> 4;
    const int m0 = blockIdx.x * 64 + wave * 16;
    const int o0 = blockIdx.y * 64;

    floatx4 acc[4] = {};
    #pragma unroll
    for (int cc = 0; cc < 8; ++cc) {
        const int c0 = cc * 32;
        short8 a = *reinterpret_cast<const short8*>(tokT + (size_t)(m0 + l16) * 256 + c0 + quad * 8);
        #pragma unroll
        for (int t4 = 0; t4 < 4; ++t4) {
            short8 b = *reinterpret_cast<const short8*>(w + (size_t)(o0 + t4 * 16 + l16) * 256 + c0 + quad * 8);
            acc[t4] = __builtin_amdgcn_mfma_f32_16x16x32_bf16(a, b, acc[t4], 0, 0, 0);
        }
    }
    #pragma unroll
    for (int t4 = 0; t4 < 4; ++t4) {
        #pragma unroll
        for (int r = 0; r < 4; ++r) {
            const int n = m0 + quad * 4 + r;
            const int o = o0 + t4 * 16 + l16;
            const unsigned short val = f2bf(acc[t4][r]);
            const int s = o >> 8, rem = o & 255, head = rem >> 5, t = rem & 31;
            if (s == 0)       qm[((size_t)head * 4096 + n) * 32 + t] = val;
            else if (s == 1)  km[((size_t)head * 4096 + n) * 32 + t] = val;
            else              vt[((size_t)head * 32 + t) * 4096 + n] = val;
        }
    }
}

// ---------------- 3) flash attention with local-3D mask + tile skip ----------------
__global__ __launch_bounds__(256) void k_attn(const unsigned short* __restrict__ qm,
                                              const unsigned short* __restrict__ km,
                                              const unsigned short* __restrict__ vt,
                                              unsigned short* __restrict__ ao) {
    const int h  = blockIdx.y;
    const int n0 = blockIdx.x * 64;
    const int tid = threadIdx.x;
    const int wave = tid >> 6, lane = tid & 63;
    const int l16 = lane & 15, quad = lane >> 4;
    const int m0 = n0 + wave * 16;

    __shared__ unsigned short pbuf[4][16][72];

    short8 a_q = *reinterpret_cast<const short8*>(qm + ((size_t)h * 4096 + m0 + l16) * 32 + quad * 8);

    // wave-uniform query coords: all 16 rows share (d,h); w = quad*4+r (m0 16-aligned)
    const int hq = (m0 >> 4) & 15, dq = m0 >> 8;
    float dw2[4];
    #pragma unroll
    for (int r = 0; r < 4; ++r) {
        const float dw = (float)(quad * 4 + r - l16);
        dw2[r] = dw * dw;
    }

    float m_i[4], l_i[4];
    floatx4 o_acc[2] = {};
    #pragma unroll
    for (int r = 0; r < 4; ++r) { m_i[r] = NEG_BIG; l_i[r] = 0.f; }

    const float scale2 = 0.17677669529663687f * L2E;   // (1/sqrt(32)) * log2(e)

    for (int it = 0; it < 64; ++it) {
        const int j0 = (n0 + it * 64) & 4095;   // diagonal tile first (it=0 never skipped)
        const int dk = j0 >> 8, hk0 = (j0 >> 4) & 15;
        const int dd = dq - dk;
        // whole-tile skip: min dist^2 over tile (dw_min=0, h spans hk0..hk0+3)
        int dh_min = 0;
        if (hq < hk0) dh_min = hk0 - hq;
        else if (hq > hk0 + 3) dh_min = hq - hk0 - 3;
        if (dd * dd + dh_min * dh_min >= 100) continue;

        // per-subtile mask threshold: dw2 < 100 - dd^2 - dh^2  (scalar per t4)
        float thr[4];
        #pragma unroll
        for (int t4 = 0; t4 < 4; ++t4) {
            const int dh = hq - (hk0 + t4);
            thr[t4] = (float)(100 - dd * dd - dh * dh);
        }

        float s[4][4];
        #pragma unroll
        for (int t4 = 0; t4 < 4; ++t4) {
            short8 b_k = *reinterpret_cast<const short8*>(km + ((size_t)h * 4096 + j0 + t4 * 16 + l16) * 32 + quad * 8);
            floatx4 sf = __builtin_amdgcn_mfma_f32_16x16x32_bf16(a_q, b_k, (floatx4){0.f, 0.f, 0.f, 0.f}, 0, 0, 0);
            #pragma unroll
            for (int r = 0; r < 4; ++r)
                s[t4][r] = (dw2[r] < thr[t4]) ? sf[r] * scale2 : NEG_BIG;
        }

        float p[4][4], alpha[4];
        #pragma unroll
        for (int r = 0; r < 4; ++r) {
            float mx = fmaxf(fmaxf(s[0][r], s[1][r]), fmaxf(s[2][r], s[3][r]));
            #pragma unroll
            for (int off = 1; off < 16; off <<= 1) mx = fmaxf(mx, __shfl_xor(mx, off));
            const float m_new = fmaxf(m_i[r], mx);
            alpha[r] = exp2f(m_i[r] - m_new);
            m_i[r] = m_new;
            float rs = 0.f;
            #pragma unroll
            for (int t4 = 0; t4 < 4; ++t4) {
                const float pv = exp2f(s[t4][r] - m_new);
                p[t4][r] = pv;
                rs += pv;
            }
            #pragma unroll
            for (int off = 1; off < 16; off <<= 1) rs += __shfl_xor(rs, off);
            l_i[r] = l_i[r] * alpha[r] + rs;
        }
        #pragma unroll
        for (int tt = 0; tt < 2; ++tt)
            #pragma unroll
            for (int r = 0; r < 4; ++r) o_acc[tt][r] *= alpha[r];

        #pragma unroll
        for (int t4 = 0; t4 < 4; ++t4)
            #pragma unroll
            for (int r = 0; r < 4; ++r)
                pbuf[wave][quad * 4 + r][t4 * 16 + l16] = f2bf(p[t4][r]);

        #pragma unroll
        for (int kt = 0; kt < 2; ++kt) {
            short8 a_p = *reinterpret_cast<const short8*>(&pbuf[wave][l16][kt * 32 + quad * 8]);
            #pragma unroll
            for (int tt = 0; tt < 2; ++tt) {
                short8 b_v = *reinterpret_cast<const short8*>(
                    vt + ((size_t)h * 32 + tt * 16 + l16) * 4096 + j0 + kt * 32 + quad * 8);
                o_acc[tt] = __builtin_amdgcn_mfma_f32_16x16x32_bf16(a_p, b_v, o_acc[tt], 0, 0, 0);
            }
        }
    }

    #pragma unroll
    for (int r = 0; r < 4; ++r) {
        const float inv = 1.0f / l_i[r];
        const int n = m0 + quad * 4 + r;
        #pragma unroll
        for (int tt = 0; tt < 2; ++tt)
            ao[(size_t)n * 256 + h * 32 + tt * 16 + l16] = f2bf(o_acc[tt][r] * inv);
    }
}

// ---------------- 4) proj GEMM + bias: out[o][n] (fp32) ----------------
__global__ __launch_bounds__(256) void k_proj(const unsigned short* __restrict__ ao,
                                              const unsigned short* __restrict__ pw,
                                              const float* __restrict__ pb,
                                              float* __restrict__ out) {
    const int tid = threadIdx.x;
    const int wave = tid >> 6, lane = tid & 63;
    const int l16 = lane & 15, quad = lane >> 4;
    const int n0 = blockIdx.x * 64;
    const int m0 = blockIdx.y * 64 + wave * 16;

    floatx4 acc[4] = {};
    #pragma unroll
    for (int cc = 0; cc < 8; ++cc) {
        const int c0 = cc * 32;
        short8 a = *reinterpret_cast<const short8*>(pw + (size_t)(m0 + l16) * 256 + c0 + quad * 8);
        #pragma unroll
        for (int t4 = 0; t4 < 4; ++t4) {
            short8 b = *reinterpret_cast<const short8*>(ao + (size_t)(n0 + t4 * 16 + l16) * 256 + c0 + quad * 8);
            acc[t4] = __builtin_amdgcn_mfma_f32_16x16x32_bf16(a, b, acc[t4], 0, 0, 0);
        }
    }
    #pragma unroll
    for (int t4 = 0; t4 < 4; ++t4) {
        #pragma unroll
        for (int r = 0; r < 4; ++r) {
            const int o = m0 + quad * 4 + r;
            const int n = n0 + t4 * 16 + l16;
            out[(size_t)o * 4096 + n] = acc[t4][r] + pb[o];   // FP32 output
        }
    }
}

extern "C" void kernel_launch(void* const* d_in, const int* in_sizes, int n_in,
                              void* d_out, int out_size, void* d_ws, size_t ws_size,
                              hipStream_t stream) {
    const float* x      = (const float*)d_in[0];
    const float* qkv_w  = (const float*)d_in[1];
    const float* proj_w = (const float*)d_in[2];
    const float* proj_b = (const float*)d_in[3];
    float* out = (float*)d_out;                    // [256,4096] fp32

    unsigned short* ws   = (unsigned short*)d_ws;
    const size_t M = 1u << 20;
    unsigned short* tokT = ws;           // [4096][256] bf16
    unsigned short* qm   = ws + 1 * M;   // [8][4096][32]
    unsigned short* km   = ws + 2 * M;   // [8][4096][32]
    unsigned short* vt   = ws + 3 * M;   // [8][32][4096]
    unsigned short* ao   = ws + 4 * M;   // [4096][256]
    unsigned short* wqb  = ws + 5 * M;               // [768][256] bf16
    unsigned short* wpb  = ws + 5 * M + 768 * 256;   // [256][256] bf16

    k_cvt<<<dim3(192), 256, 0, stream>>>(qkv_w, wqb, 768 * 256 / 4);
    k_cvt<<<dim3(64), 256, 0, stream>>>(proj_w, wpb, 256 * 256 / 4);
    k_transpose<<<dim3(64, 4), 256, 0, stream>>>(x, tokT);
    k_qkv<<<dim3(64, 12), 256, 0, stream>>>(tokT, wqb, qm, km, vt);
    k_attn<<<dim3(64, 8), 256, 0, stream>>>(qm, km, vt, ao);
    k_proj<<<dim3(64, 4), 256, 0, stream>>>(ao, wpb, proj_b, out);
}

// Round 9
// 178.842 us; speedup vs baseline: 22.0422x; 1.1549x over previous
//
#include <hip/hip_runtime.h>

typedef __attribute__((ext_vector_type(8))) short short8;
typedef __attribute__((ext_vector_type(8))) unsigned short ushort8;
typedef __attribute__((ext_vector_type(4))) unsigned short ushort4v;
typedef __attribute__((ext_vector_type(4))) float floatx4;

#define L2E 1.4426950408889634f

static __device__ __forceinline__ float bf2f(unsigned short u) {
    unsigned int v = ((unsigned int)u) << 16;
    return __builtin_bit_cast(float, v);
}
static __device__ __forceinline__ unsigned short f2bf(float f) {
    unsigned int u = __builtin_bit_cast(unsigned int, f);
    u += 0x7fffu + ((u >> 16) & 1u);   // RNE
    return (unsigned short)(u >> 16);
}
static __device__ __forceinline__ unsigned int pk_bf16(float a, float b) {
    return (unsigned int)f2bf(a) | ((unsigned int)f2bf(b) << 16);   // low16 = a, high16 = b
}

// ---------------- 1) prep: transpose+cast x, convert weights (fused, 1 dispatch) ----------------
__global__ __launch_bounds__(256) void k_prep(const float* __restrict__ x,
                                              const float* __restrict__ qw,
                                              const float* __restrict__ pw,
                                              unsigned short* __restrict__ tokT,
                                              unsigned short* __restrict__ wqb,
                                              unsigned short* __restrict__ wpb) {
    __shared__ unsigned short tile[64][72];
    const int b = blockIdx.x, tid = threadIdx.x;
    if (b < 256) {            // transpose x[256][4096] -> tokT[4096][256] bf16
        const int n0 = (b & 63) * 64, c0 = (b >> 6) * 64;
        {
            const int c_l = tid >> 2, nl0 = (tid & 3) * 16;
            const float4* src = reinterpret_cast<const float4*>(x + (size_t)(c0 + c_l) * 4096 + n0 + nl0);
            #pragma unroll
            for (int v = 0; v < 4; ++v) {
                const float4 f = src[v];
                tile[c_l][nl0 + v * 4 + 0] = f2bf(f.x);
                tile[c_l][nl0 + v * 4 + 1] = f2bf(f.y);
                tile[c_l][nl0 + v * 4 + 2] = f2bf(f.z);
                tile[c_l][nl0 + v * 4 + 3] = f2bf(f.w);
            }
        }
        __syncthreads();
        {
            const int n_l = tid >> 2, cl0 = (tid & 3) * 16;
            ushort8 a, c;
            #pragma unroll
            for (int i = 0; i < 8; ++i) {
                a[i] = tile[cl0 + i][n_l];
                c[i] = tile[cl0 + 8 + i][n_l];
            }
            ushort8* dst = reinterpret_cast<ushort8*>(tokT + (size_t)(n0 + n_l) * 256 + c0 + cl0);
            dst[0] = a;
            dst[1] = c;
        }
    } else if (b < 448) {     // cvt qkv_w: 192 blocks, 49152 float4
        const int i = (b - 256) * 256 + tid;
        const float4 v = reinterpret_cast<const float4*>(qw)[i];
        ushort4v o;
        o[0] = f2bf(v.x); o[1] = f2bf(v.y); o[2] = f2bf(v.z); o[3] = f2bf(v.w);
        reinterpret_cast<ushort4v*>(wqb)[i] = o;
    } else {                  // cvt proj_w: 64 blocks, 16384 float4
        const int i = (b - 448) * 256 + tid;
        const float4 v = reinterpret_cast<const float4*>(pw)[i];
        ushort4v o;
        o[0] = f2bf(v.x); o[1] = f2bf(v.y); o[2] = f2bf(v.z); o[3] = f2bf(v.w);
        reinterpret_cast<ushort4v*>(wpb)[i] = o;
    }
}

// ---------------- 2) QKV GEMM ----------------
__global__ __launch_bounds__(256) void k_qkv(const unsigned short* __restrict__ tokT,
                                             const unsigned short* __restrict__ w,
                                             unsigned short* __restrict__ qm,
                                             unsigned short* __restrict__ km,
                                             unsigned short* __restrict__ vt) {
    const int tid = threadIdx.x;
    const int wave = tid >> 6, lane = tid & 63;
    const int l16 = lane & 15, quad = lane >> 4;
    const int m0 = blockIdx.x * 64 + wave * 16;
    const int o0 = blockIdx.y * 64;

    floatx4 acc[4] = {};
    #pragma unroll
    for (int cc = 0; cc < 8; ++cc) {
        const int c0 = cc * 32;
        short8 a = *reinterpret_cast<const short8*>(tokT + (size_t)(m0 + l16) * 256 + c0 + quad * 8);
        #pragma unroll
        for (int t4 = 0; t4 < 4; ++t4) {
            short8 b = *reinterpret_cast<const short8*>(w + (size_t)(o0 + t4 * 16 + l16) * 256 + c0 + quad * 8);
            acc[t4] = __builtin_amdgcn_mfma_f32_16x16x32_bf16(a, b, acc[t4], 0, 0, 0);
        }
    }
    #pragma unroll
    for (int t4 = 0; t4 < 4; ++t4) {
        #pragma unroll
        for (int r = 0; r < 4; ++r) {
            const int n = m0 + quad * 4 + r;
            const int o = o0 + t4 * 16 + l16;
            const unsigned short val = f2bf(acc[t4][r]);
            const int s = o >> 8, rem = o & 255, head = rem >> 5, t = rem & 31;
            if (s == 0)       qm[((size_t)head * 4096 + n) * 32 + t] = val;
            else if (s == 1)  km[((size_t)head * 4096 + n) * 32 + t] = val;
            else              vt[((size_t)head * 32 + t) * 4096 + n] = val;
        }
    }
}

// ---------------- 3) flash attention, no-max softmax, split-K ----------------
__global__ __launch_bounds__(256) void k_attn(const unsigned short* __restrict__ qm,
                                              const unsigned short* __restrict__ km,
                                              const unsigned short* __restrict__ vt,
                                              unsigned short* __restrict__ op0,
                                              unsigned short* __restrict__ op1,
                                              unsigned short* __restrict__ op2,
                                              unsigned short* __restrict__ op3,
                                              float* __restrict__ lpart, int K) {
    const int h  = blockIdx.y;
    const int n0 = blockIdx.x * 64;
    const int z  = blockIdx.z;
    const int tid = threadIdx.x;
    const int wave = tid >> 6, lane = tid & 63;
    const int l16 = lane & 15, quad = lane >> 4;
    const int m0 = n0 + wave * 16;

    __shared__ unsigned short pbuf[4][16][72];

    short8 a_q = *reinterpret_cast<const short8*>(qm + ((size_t)h * 4096 + m0 + l16) * 32 + quad * 8);

    const int hq = (m0 >> 4) & 15, dq = m0 >> 8;
    float dw2[4];
    #pragma unroll
    for (int r = 0; r < 4; ++r) {
        const float dw = (float)(quad * 4 + r - l16);
        dw2[r] = dw * dw;
    }

    float l_acc[4] = {0.f, 0.f, 0.f, 0.f};
    floatx4 o_acc[2] = {};
    const float scale2 = 0.17677669529663687f * L2E;   // (1/sqrt(32)) * log2(e)
    const int iters = 64 / K;

    for (int it = 0; it < iters; ++it) {
        const int j0 = (n0 + (it * K + z) * 64) & 4095;   // interleaved split-K: balanced
        const int dk = j0 >> 8, hk0 = (j0 >> 4) & 15;
        const int dd = dq - dk;
        int dh_min = 0;
        if (hq < hk0) dh_min = hk0 - hq;
        else if (hq > hk0 + 3) dh_min = hq - hk0 - 3;
        if (dd * dd + dh_min * dh_min >= 100) continue;   // whole-tile skip

        int thr[4];
        #pragma unroll
        for (int t4 = 0; t4 < 4; ++t4) {
            const int dh = hq - (hk0 + t4);
            thr[t4] = 100 - dd * dd - dh * dh;
        }

        // S = QK^T per 16-key subtile; p = exp2(s*scale2) masked; no max subtraction
        #pragma unroll
        for (int t4 = 0; t4 < 4; ++t4) {
            const bool sib = (thr[t4 ^ 1] > 0);   // sibling subtile of this kt alive?
            if (thr[t4] > 0) {
                short8 b_k = *reinterpret_cast<const short8*>(
                    km + ((size_t)h * 4096 + j0 + t4 * 16 + l16) * 32 + quad * 8);
                floatx4 sf = __builtin_amdgcn_mfma_f32_16x16x32_bf16(
                    a_q, b_k, (floatx4){0.f, 0.f, 0.f, 0.f}, 0, 0, 0);
                const float thrf = (float)thr[t4];
                float p[4];
                #pragma unroll
                for (int r = 0; r < 4; ++r) {
                    p[r] = (dw2[r] < thrf) ? exp2f(sf[r] * scale2) : 0.f;
                    l_acc[r] += p[r];
                }
                const unsigned int u01 = pk_bf16(p[0], p[1]);
                const unsigned int u23 = pk_bf16(p[2], p[3]);
                pbuf[wave][quad * 4 + 0][t4 * 16 + l16] = (unsigned short)u01;
                pbuf[wave][quad * 4 + 1][t4 * 16 + l16] = (unsigned short)(u01 >> 16);
                pbuf[wave][quad * 4 + 2][t4 * 16 + l16] = (unsigned short)u23;
                pbuf[wave][quad * 4 + 3][t4 * 16 + l16] = (unsigned short)(u23 >> 16);
            } else if (sib) {   // dead subtile inside a live kt: zero-fill P
                #pragma unroll
                for (int r = 0; r < 4; ++r)
                    pbuf[wave][quad * 4 + r][t4 * 16 + l16] = 0;
            }
        }

        #pragma unroll
        for (int kt = 0; kt < 2; ++kt) {
            if (thr[2 * kt] <= 0 && thr[2 * kt + 1] <= 0) continue;   // dead kt: skip PV
            short8 a_p = *reinterpret_cast<const short8*>(&pbuf[wave][l16][kt * 32 + quad * 8]);
            #pragma unroll
            for (int tt = 0; tt < 2; ++tt) {
                short8 b_v = *reinterpret_cast<const short8*>(
                    vt + ((size_t)h * 32 + tt * 16 + l16) * 4096 + j0 + kt * 32 + quad * 8);
                o_acc[tt] = __builtin_amdgcn_mfma_f32_16x16x32_bf16(a_p, b_v, o_acc[tt], 0, 0, 0);
            }
        }
    }

    // deferred l reduction (once): sum over the 16 lanes of each quad-row group
    #pragma unroll
    for (int r = 0; r < 4; ++r) {
        #pragma unroll
        for (int off = 1; off < 16; off <<= 1) l_acc[r] += __shfl_xor(l_acc[r], off);
    }
    if (l16 == 0) {
        #pragma unroll
        for (int r = 0; r < 4; ++r)
            lpart[((size_t)z * 8 + h) * 4096 + m0 + quad * 4 + r] = l_acc[r];
    }

    unsigned short* op = (z == 0) ? op0 : (z == 1) ? op1 : (z == 2) ? op2 : op3;
    #pragma unroll
    for (int r = 0; r < 4; ++r) {
        const int n = m0 + quad * 4 + r;
        #pragma unroll
        for (int tt = 0; tt < 2; ++tt)
            op[(size_t)n * 256 + h * 32 + tt * 16 + l16] = f2bf(o_acc[tt][r]);
    }
}

// ---------------- 3b) merge split-K partials -> ao bf16 [n][256] ----------------
__global__ __launch_bounds__(256) void k_merge(const unsigned short* __restrict__ op0,
                                               const unsigned short* __restrict__ op1,
                                               const unsigned short* __restrict__ op2,
                                               const unsigned short* __restrict__ op3,
                                               const float* __restrict__ lpart,
                                               unsigned short* __restrict__ ao, int K) {
    const int gid = blockIdx.x * 256 + threadIdx.x;   // 131072 threads, 8 elems each
    const int n = gid >> 5, c8 = (gid & 31) * 8, h = c8 >> 5;
    const size_t off = (size_t)n * 256 + c8;

    float l = lpart[(size_t)h * 4096 + n];
    float acc[8];
    {
        const ushort8 v = *reinterpret_cast<const ushort8*>(op0 + off);
        #pragma unroll
        for (int j = 0; j < 8; ++j) acc[j] = bf2f(v[j]);
    }
    {
        l += lpart[((size_t)8 + h) * 4096 + n];
        const ushort8 v = *reinterpret_cast<const ushort8*>(op1 + off);
        #pragma unroll
        for (int j = 0; j < 8; ++j) acc[j] += bf2f(v[j]);
    }
    if (K == 4) {
        l += lpart[((size_t)16 + h) * 4096 + n] + lpart[((size_t)24 + h) * 4096 + n];
        const ushort8 v2 = *reinterpret_cast<const ushort8*>(op2 + off);
        const ushort8 v3 = *reinterpret_cast<const ushort8*>(op3 + off);
        #pragma unroll
        for (int j = 0; j < 8; ++j) acc[j] += bf2f(v2[j]) + bf2f(v3[j]);
    }
    const float inv = 1.0f / l;
    ushort8 o;
    #pragma unroll
    for (int j = 0; j < 8; ++j) o[j] = f2bf(acc[j] * inv);
    *reinterpret_cast<ushort8*>(ao + off) = o;
}

// ---------------- 4) proj GEMM + bias: out[o][n] fp32 ----------------
__global__ __launch_bounds__(256) void k_proj(const unsigned short* __restrict__ ao,
                                              const unsigned short* __restrict__ pw,
                                              const float* __restrict__ pb,
                                              float* __restrict__ out) {
    const int tid = threadIdx.x;
    const int wave = tid >> 6, lane = tid & 63;
    const int l16 = lane & 15, quad = lane >> 4;
    const int n0 = blockIdx.x * 64;
    const int m0 = blockIdx.y * 64 + wave * 16;

    floatx4 acc[4] = {};
    #pragma unroll
    for (int cc = 0; cc < 8; ++cc) {
        const int c0 = cc * 32;
        short8 a = *reinterpret_cast<const short8*>(pw + (size_t)(m0 + l16) * 256 + c0 + quad * 8);
        #pragma unroll
        for (int t4 = 0; t4 < 4; ++t4) {
            short8 b = *reinterpret_cast<const short8*>(ao + (size_t)(n0 + t4 * 16 + l16) * 256 + c0 + quad * 8);
            acc[t4] = __builtin_amdgcn_mfma_f32_16x16x32_bf16(a, b, acc[t4], 0, 0, 0);
        }
    }
    #pragma unroll
    for (int t4 = 0; t4 < 4; ++t4) {
        #pragma unroll
        for (int r = 0; r < 4; ++r) {
            const int o = m0 + quad * 4 + r;
            const int n = n0 + t4 * 16 + l16;
            out[(size_t)o * 4096 + n] = acc[t4][r] + pb[o];
        }
    }
}

extern "C" void kernel_launch(void* const* d_in, const int* in_sizes, int n_in,
                              void* d_out, int out_size, void* d_ws, size_t ws_size,
                              hipStream_t stream) {
    const float* x      = (const float*)d_in[0];
    const float* qkv_w  = (const float*)d_in[1];
    const float* proj_w = (const float*)d_in[2];
    const float* proj_b = (const float*)d_in[3];
    float* out = (float*)d_out;                    // [256,4096] fp32

    unsigned short* ws = (unsigned short*)d_ws;
    const size_t M = 1u << 20;
    unsigned short* tokT = ws;                       // [4096][256] bf16; dead after qkv -> opart1
    unsigned short* qm   = ws + 1 * M;
    unsigned short* km   = ws + 2 * M;
    unsigned short* vt   = ws + 3 * M;
    unsigned short* ao   = ws + 4 * M;               // opart0, merged in-place
    unsigned short* wqb  = ws + 5 * M;               // [768][256]; dead after qkv -> lpart (K=2)
    unsigned short* wpb  = ws + 5 * M + 768 * 256;
    unsigned short* ext  = ws + 5 * M + 768 * 256 + 256 * 256;   // 11,010,048 B mark

    // K=4 needs ext: opart2 (2MB) + opart3 (2MB) + lpart (512KB) -> ws_size >= 15,728,640 B
    const int K = (ws_size >= 15728640u) ? 4 : 2;
    unsigned short* op2 = (K == 4) ? ext : ws;
    unsigned short* op3 = (K == 4) ? ext + M : ws;
    float* lpart = (K == 4) ? (float*)(ext + 2 * M) : (float*)wqb;

    k_prep<<<dim3(512), 256, 0, stream>>>(x, qkv_w, proj_w, tokT, wqb, wpb);
    k_qkv<<<dim3(64, 12), 256, 0, stream>>>(tokT, wqb, qm, km, vt);
    k_attn<<<dim3(64, 8, K), 256, 0, stream>>>(qm, km, vt, ao, tokT, op2, op3, lpart, K);
    k_merge<<<dim3(512), 256, 0, stream>>>(ao, tokT, op2, op3, lpart, ao, K);
    k_proj<<<dim3(64, 4), 256, 0, stream>>>(ao, wpb, proj_b, out);
}

// Round 10
// 177.488 us; speedup vs baseline: 22.2103x; 1.0076x over previous
//
#include <hip/hip_runtime.h>
#include <hip/hip_bf16.h>

typedef __attribute__((ext_vector_type(8))) short short8;
typedef __attribute__((ext_vector_type(8))) unsigned short ushort8;
typedef __attribute__((ext_vector_type(4))) unsigned short ushort4v;
typedef __attribute__((ext_vector_type(4))) float floatx4;

#define L2E 1.4426950408889634f

#if __has_builtin(__builtin_amdgcn_exp2f)
#define EXP2(x) __builtin_amdgcn_exp2f(x)
#else
#define EXP2(x) exp2f(x)
#endif

static __device__ __forceinline__ float bf2f(unsigned short u) {
    unsigned int v = ((unsigned int)u) << 16;
    return __builtin_bit_cast(float, v);
}
static __device__ __forceinline__ unsigned short f2bf(float f) {
    unsigned int u = __builtin_bit_cast(unsigned int, f);
    u += 0x7fffu + ((u >> 16) & 1u);   // RNE
    return (unsigned short)(u >> 16);
}
static __device__ __forceinline__ unsigned int pk_bf16(float a, float b) {
    __hip_bfloat162 h2 = __float22bfloat162_rn(make_float2(a, b));   // v_cvt_pk_bf16_f32
    unsigned int u;
    __builtin_memcpy(&u, &h2, 4);     // low16 = a, high16 = b
    return u;
}
static __device__ __forceinline__ void atomf(float* p, float v) {
    __hip_atomic_fetch_add(p, v, __ATOMIC_RELAXED, __HIP_MEMORY_SCOPE_AGENT);
}

// ---------------- 1) prep: transpose+cast x, convert weights ----------------
__global__ __launch_bounds__(256) void k_prep(const float* __restrict__ x,
                                              const float* __restrict__ qw,
                                              const float* __restrict__ pw,
                                              unsigned short* __restrict__ tokT,
                                              unsigned short* __restrict__ wqb,
                                              unsigned short* __restrict__ wpb) {
    __shared__ unsigned short tile[64][72];
    const int b = blockIdx.x, tid = threadIdx.x;
    if (b < 256) {            // transpose x[256][4096] -> tokT[4096][256] bf16
        const int n0 = (b & 63) * 64, c0 = (b >> 6) * 64;
        {
            const int c_l = tid >> 2, nl0 = (tid & 3) * 16;
            const float4* src = reinterpret_cast<const float4*>(x + (size_t)(c0 + c_l) * 4096 + n0 + nl0);
            #pragma unroll
            for (int v = 0; v < 4; ++v) {
                const float4 f = src[v];
                tile[c_l][nl0 + v * 4 + 0] = f2bf(f.x);
                tile[c_l][nl0 + v * 4 + 1] = f2bf(f.y);
                tile[c_l][nl0 + v * 4 + 2] = f2bf(f.z);
                tile[c_l][nl0 + v * 4 + 3] = f2bf(f.w);
            }
        }
        __syncthreads();
        {
            const int n_l = tid >> 2, cl0 = (tid & 3) * 16;
            ushort8 a, c;
            #pragma unroll
            for (int i = 0; i < 8; ++i) {
                a[i] = tile[cl0 + i][n_l];
                c[i] = tile[cl0 + 8 + i][n_l];
            }
            ushort8* dst = reinterpret_cast<ushort8*>(tokT + (size_t)(n0 + n_l) * 256 + c0 + cl0);
            dst[0] = a;
            dst[1] = c;
        }
    } else if (b < 448) {     // cvt qkv_w
        const int i = (b - 256) * 256 + tid;
        const float4 v = reinterpret_cast<const float4*>(qw)[i];
        ushort4v o;
        o[0] = f2bf(v.x); o[1] = f2bf(v.y); o[2] = f2bf(v.z); o[3] = f2bf(v.w);
        reinterpret_cast<ushort4v*>(wqb)[i] = o;
    } else {                  // cvt proj_w
        const int i = (b - 448) * 256 + tid;
        const float4 v = reinterpret_cast<const float4*>(pw)[i];
        ushort4v o;
        o[0] = f2bf(v.x); o[1] = f2bf(v.y); o[2] = f2bf(v.z); o[3] = f2bf(v.w);
        reinterpret_cast<ushort4v*>(wpb)[i] = o;
    }
}

// ---------------- 2) QKV GEMM ----------------
__global__ __launch_bounds__(256) void k_qkv(const unsigned short* __restrict__ tokT,
                                             const unsigned short* __restrict__ w,
                                             unsigned short* __restrict__ qm,
                                             unsigned short* __restrict__ km,
                                             unsigned short* __restrict__ vt) {
    const int tid = threadIdx.x;
    const int wave = tid >> 6, lane = tid & 63;
    const int l16 = lane & 15, quad = lane >> 4;
    const int m0 = blockIdx.x * 64 + wave * 16;
    const int o0 = blockIdx.y * 64;

    floatx4 acc[4] = {};
    #pragma unroll
    for (int cc = 0; cc < 8; ++cc) {
        const int c0 = cc * 32;
        short8 a = *reinterpret_cast<const short8*>(tokT + (size_t)(m0 + l16) * 256 + c0 + quad * 8);
        #pragma unroll
        for (int t4 = 0; t4 < 4; ++t4) {
            short8 b = *reinterpret_cast<const short8*>(w + (size_t)(o0 + t4 * 16 + l16) * 256 + c0 + quad * 8);
            acc[t4] = __builtin_amdgcn_mfma_f32_16x16x32_bf16(a, b, acc[t4], 0, 0, 0);
        }
    }
    #pragma unroll
    for (int t4 = 0; t4 < 4; ++t4) {
        #pragma unroll
        for (int r = 0; r < 4; ++r) {
            const int n = m0 + quad * 4 + r;
            const int o = o0 + t4 * 16 + l16;
            const unsigned short val = f2bf(acc[t4][r]);
            const int s = o >> 8, rem = o & 255, head = rem >> 5, t = rem & 31;
            if (s == 0)       qm[((size_t)head * 4096 + n) * 32 + t] = val;
            else if (s == 1)  km[((size_t)head * 4096 + n) * 32 + t] = val;
            else              vt[((size_t)head * 32 + t) * 4096 + n] = val;
        }
    }
}

// ---------------- 2b) zero O/l accumulators (runs after qkv: region overlays tokT/wqb) ----
__global__ __launch_bounds__(256) void k_zero(float4* __restrict__ Of4, float4* __restrict__ lf4) {
    const int i = blockIdx.x * 256 + threadIdx.x;
    const float4 z = make_float4(0.f, 0.f, 0.f, 0.f);
    if (i < 262144) Of4[i] = z;                       // 4 MB O accumulator
    else if (i < 270336) lf4[i - 262144] = z;         // 128 KB l accumulator
}

// ---------------- 3) flash attention: no-max softmax, atomic split-K (K=4) ----------------
__global__ __launch_bounds__(256) void k_attn(const unsigned short* __restrict__ qm,
                                              const unsigned short* __restrict__ km,
                                              const unsigned short* __restrict__ vt,
                                              float* __restrict__ Of,
                                              float* __restrict__ lf) {
    const int h  = blockIdx.y;
    const int n0 = blockIdx.x * 64;
    const int z  = blockIdx.z;
    const int tid = threadIdx.x;
    const int wave = tid >> 6, lane = tid & 63;
    const int l16 = lane & 15, quad = lane >> 4;
    const int m0 = n0 + wave * 16;

    __shared__ unsigned short pbuf[4][16][72];

    short8 a_q = *reinterpret_cast<const short8*>(qm + ((size_t)h * 4096 + m0 + l16) * 32 + quad * 8);

    const int hq = (m0 >> 4) & 15, dq = m0 >> 8;
    float dw2[4];
    #pragma unroll
    for (int r = 0; r < 4; ++r) {
        const float dw = (float)(quad * 4 + r - l16);
        dw2[r] = dw * dw;
    }

    float l_acc[4] = {0.f, 0.f, 0.f, 0.f};
    floatx4 o_acc[2] = {};
    const float scale2 = 0.17677669529663687f * L2E;   // (1/sqrt(32)) * log2(e)

    for (int it = 0; it < 16; ++it) {
        const int j0 = (n0 + (it * 4 + z) * 64) & 4095;   // interleaved split-K
        const int dk = j0 >> 8, hk0 = (j0 >> 4) & 15;
        const int dd = dq - dk;
        int dh_min = 0;
        if (hq < hk0) dh_min = hk0 - hq;
        else if (hq > hk0 + 3) dh_min = hq - hk0 - 3;
        if (dd * dd + dh_min * dh_min >= 100) continue;   // whole-tile skip

        int thr[4];
        #pragma unroll
        for (int t4 = 0; t4 < 4; ++t4) {
            const int dh = hq - (hk0 + t4);
            thr[t4] = 100 - dd * dd - dh * dh;
        }

        #pragma unroll
        for (int t4 = 0; t4 < 4; ++t4) {
            const bool sib = (thr[t4 ^ 1] > 0);
            if (thr[t4] > 0) {
                short8 b_k = *reinterpret_cast<const short8*>(
                    km + ((size_t)h * 4096 + j0 + t4 * 16 + l16) * 32 + quad * 8);
                floatx4 sf = __builtin_amdgcn_mfma_f32_16x16x32_bf16(
                    a_q, b_k, (floatx4){0.f, 0.f, 0.f, 0.f}, 0, 0, 0);
                const float thrf = (float)thr[t4];
                float p[4];
                #pragma unroll
                for (int r = 0; r < 4; ++r) {
                    p[r] = (dw2[r] < thrf) ? EXP2(sf[r] * scale2) : 0.f;
                    l_acc[r] += p[r];
                }
                const unsigned int u01 = pk_bf16(p[0], p[1]);
                const unsigned int u23 = pk_bf16(p[2], p[3]);
                pbuf[wave][quad * 4 + 0][t4 * 16 + l16] = (unsigned short)u01;
                pbuf[wave][quad * 4 + 1][t4 * 16 + l16] = (unsigned short)(u01 >> 16);
                pbuf[wave][quad * 4 + 2][t4 * 16 + l16] = (unsigned short)u23;
                pbuf[wave][quad * 4 + 3][t4 * 16 + l16] = (unsigned short)(u23 >> 16);
            } else if (sib) {
                #pragma unroll
                for (int r = 0; r < 4; ++r)
                    pbuf[wave][quad * 4 + r][t4 * 16 + l16] = 0;
            }
        }

        #pragma unroll
        for (int kt = 0; kt < 2; ++kt) {
            if (thr[2 * kt] <= 0 && thr[2 * kt + 1] <= 0) continue;
            short8 a_p = *reinterpret_cast<const short8*>(&pbuf[wave][l16][kt * 32 + quad * 8]);
            #pragma unroll
            for (int tt = 0; tt < 2; ++tt) {
                short8 b_v = *reinterpret_cast<const short8*>(
                    vt + ((size_t)h * 32 + tt * 16 + l16) * 4096 + j0 + kt * 32 + quad * 8);
                o_acc[tt] = __builtin_amdgcn_mfma_f32_16x16x32_bf16(a_p, b_v, o_acc[tt], 0, 0, 0);
            }
        }
    }

    // l: one shuffle-reduce per row, then 4 atomics from the l16==0 lanes
    #pragma unroll
    for (int r = 0; r < 4; ++r) {
        #pragma unroll
        for (int off = 1; off < 16; off <<= 1) l_acc[r] += __shfl_xor(l_acc[r], off);
    }
    if (l16 == 0) {
        #pragma unroll
        for (int r = 0; r < 4; ++r)
            atomf(&lf[(size_t)h * 4096 + m0 + quad * 4 + r], l_acc[r]);
    }
    // O: fire-and-forget fp32 atomics (8 per lane)
    #pragma unroll
    for (int r = 0; r < 4; ++r) {
        const int n = m0 + quad * 4 + r;
        #pragma unroll
        for (int tt = 0; tt < 2; ++tt)
            atomf(&Of[(size_t)n * 256 + h * 32 + tt * 16 + l16], o_acc[tt][r]);
    }
}

// ---------------- 3b) normalize: Of/l -> ao bf16 [n][256] ----------------
__global__ __launch_bounds__(256) void k_norm(const float* __restrict__ Of,
                                              const float* __restrict__ lf,
                                              unsigned short* __restrict__ ao) {
    const int gid = blockIdx.x * 256 + threadIdx.x;   // 262144 threads, 4 floats each
    const int n = gid >> 6, c4 = (gid & 63) * 4, h = c4 >> 5;
    const float inv = 1.0f / lf[(size_t)h * 4096 + n];
    const float4 v = reinterpret_cast<const float4*>(Of)[gid];
    ushort4v o;
    o[0] = f2bf(v.x * inv); o[1] = f2bf(v.y * inv);
    o[2] = f2bf(v.z * inv); o[3] = f2bf(v.w * inv);
    *reinterpret_cast<ushort4v*>(ao + (size_t)n * 256 + c4) = o;
}

// ---------------- 4) proj GEMM + bias: out[o][n] fp32 ----------------
__global__ __launch_bounds__(256) void k_proj(const unsigned short* __restrict__ ao,
                                              const unsigned short* __restrict__ pw,
                                              const float* __restrict__ pb,
                                              float* __restrict__ out) {
    const int tid = threadIdx.x;
    const int wave = tid >> 6, lane = tid & 63;
    const int l16 = lane & 15, quad = lane >> 4;
    const int n0 = blockIdx.x * 64;
    const int m0 = blockIdx.y * 64 + wave * 16;

    floatx4 acc[4] = {};
    #pragma unroll
    for (int cc = 0; cc < 8; ++cc) {
        const int c0 = cc * 32;
        short8 a = *reinterpret_cast<const short8*>(pw + (size_t)(m0 + l16) * 256 + c0 + quad * 8);
        #pragma unroll
        for (int t4 = 0; t4 < 4; ++t4) {
            short8 b = *reinterpret_cast<const short8*>(ao + (size_t)(n0 + t4 * 16 + l16) * 256 + c0 + quad * 8);
            acc[t4] = __builtin_amdgcn_mfma_f32_16x16x32_bf16(a, b, acc[t4], 0, 0, 0);
        }
    }
    #pragma unroll
    for (int t4 = 0; t4 < 4; ++t4) {
        #pragma unroll
        for (int r = 0; r < 4; ++r) {
            const int o = m0 + quad * 4 + r;
            const int n = n0 + t4 * 16 + l16;
            out[(size_t)o * 4096 + n] = acc[t4][r] + pb[o];
        }
    }
}

extern "C" void kernel_launch(void* const* d_in, const int* in_sizes, int n_in,
                              void* d_out, int out_size, void* d_ws, size_t ws_size,
                              hipStream_t stream) {
    const float* x      = (const float*)d_in[0];
    const float* qkv_w  = (const float*)d_in[1];
    const float* proj_w = (const float*)d_in[2];
    const float* proj_b = (const float*)d_in[3];
    float* out = (float*)d_out;                    // [256,4096] fp32

    char* B = (char*)d_ws;
    const size_t MB = 1u << 20;
    // layout (peak 10.625 MB, within the known-good 11.01 MB):
    // [0,2)    tokT  (dead after qkv)   \___ Of fp32 [0,4) during attn
    // [2,3.5)  wqb   (dead after qkv)   /    (+0.5 MB spare at [3.5,4))
    // [4,6)    qm    (dead after attn)  ->  ao bf16 (norm output)
    // [6,8)    km
    // [8,10)   vt
    // [10,10.5)   wpb
    // [10.5,10.625) lf fp32 [8][4096]
    unsigned short* tokT = (unsigned short*)(B);
    unsigned short* wqb  = (unsigned short*)(B + 2 * MB);
    float*          Of   = (float*)(B);
    unsigned short* qm   = (unsigned short*)(B + 4 * MB);
    unsigned short* km   = (unsigned short*)(B + 6 * MB);
    unsigned short* vt   = (unsigned short*)(B + 8 * MB);
    unsigned short* wpb  = (unsigned short*)(B + 10 * MB);
    float*          lf   = (float*)(B + 10 * MB + 512 * 1024);
    unsigned short* ao   = (unsigned short*)(B + 4 * MB);

    k_prep<<<dim3(512), 256, 0, stream>>>(x, qkv_w, proj_w, tokT, wqb, wpb);
    k_qkv<<<dim3(64, 12), 256, 0, stream>>>(tokT, wqb, qm, km, vt);
    k_zero<<<dim3(1056), 256, 0, stream>>>((float4*)Of, (float4*)lf);
    k_attn<<<dim3(64, 8, 4), 256, 0, stream>>>(qm, km, vt, Of, lf);
    k_norm<<<dim3(1024), 256, 0, stream>>>(Of, lf, ao);
    k_proj<<<dim3(64, 4), 256, 0, stream>>>(ao, wpb, proj_b, out);
}